// Round 10
// baseline (777.879 us; speedup 1.0000x reference)
//
#include <hip/hip_runtime.h>
#include <math.h>

#define NROWS 32768
#define DIM   512
#define KCODE 8192
#define DECAYF 0.99f
#define OMDF   0.01f
#define EPSF   1e-5f
#define COMMITF 0.25f
#define MARGIN 8e-4f

typedef _Float16 half8 __attribute__((ext_vector_type(8)));
typedef _Float16 half4v __attribute__((ext_vector_type(4)));
typedef _Float16 half2v __attribute__((ext_vector_type(2)));
typedef float floatx16 __attribute__((ext_vector_type(16)));

// ws layout: see round-3 comment (unchanged).

__device__ __forceinline__ float block_sum_256(float v) {
    __shared__ float sm[4];
    int lane = threadIdx.x & 63, wave = threadIdx.x >> 6;
    #pragma unroll
    for (int off = 32; off; off >>= 1) v += __shfl_down(v, off);
    if (lane == 0) sm[wave] = v;
    __syncthreads();
    if (threadIdx.x == 0) v = sm[0] + sm[1] + sm[2] + sm[3];
    return v; // valid on thread 0 only
}

// fused rownorm + hi/lo split: one pass over src (saves a full re-read).
__global__ void k_norm_split(const float* __restrict__ src, float* __restrict__ inv,
                             _Float16* __restrict__ hi, _Float16* __restrict__ lo) {
    const int wave = threadIdx.x >> 6;
    const int lane = threadIdx.x & 63;
    const int row = blockIdx.x * 4 + wave;
    const float* p = src + (size_t)row * DIM;
    const float4 f1 = *(const float4*)&p[lane * 4];
    const float4 f2 = *(const float4*)&p[256 + lane * 4];
    float s = f1.x*f1.x + f1.y*f1.y + f1.z*f1.z + f1.w*f1.w
            + f2.x*f2.x + f2.y*f2.y + f2.z*f2.z + f2.w*f2.w;
    #pragma unroll
    for (int off = 32; off; off >>= 1) s += __shfl_down(s, off);
    const float iv = __shfl(1.0f / fmaxf(sqrtf(s), 1e-12f), 0);
    if (lane == 0) inv[row] = iv;

    {
        const float n0 = f1.x * iv, n1 = f1.y * iv, n2 = f1.z * iv, n3 = f1.w * iv;
        const _Float16 h0 = (_Float16)n0, h1 = (_Float16)n1, h2 = (_Float16)n2, h3 = (_Float16)n3;
        half4v hv = {h0, h1, h2, h3};
        *(half4v*)&hi[(size_t)row * DIM + lane * 4] = hv;
        half4v lv = {(_Float16)((n0 - (float)h0) * 4096.f),
                     (_Float16)((n1 - (float)h1) * 4096.f),
                     (_Float16)((n2 - (float)h2) * 4096.f),
                     (_Float16)((n3 - (float)h3) * 4096.f)};
        *(half4v*)&lo[(size_t)row * DIM + lane * 4] = lv;
    }
    {
        const float n0 = f2.x * iv, n1 = f2.y * iv, n2 = f2.z * iv, n3 = f2.w * iv;
        const _Float16 h0 = (_Float16)n0, h1 = (_Float16)n1, h2 = (_Float16)n2, h3 = (_Float16)n3;
        half4v hv = {h0, h1, h2, h3};
        *(half4v*)&hi[(size_t)row * DIM + 256 + lane * 4] = hv;
        half4v lv = {(_Float16)((n0 - (float)h0) * 4096.f),
                     (_Float16)((n1 - (float)h1) * 4096.f),
                     (_Float16)((n2 - (float)h2) * 4096.f),
                     (_Float16)((n3 - (float)h3) * 4096.f)};
        *(half4v*)&lo[(size_t)row * DIM + 256 + lane * 4] = lv;
    }
}

__device__ __forceinline__ void gld16(const _Float16* g, _Float16* l) {
    __builtin_amdgcn_global_load_lds(
        (const __attribute__((address_space(1))) void*)g,
        (__attribute__((address_space(3))) void*)l, 16, 0, 0);
}

__device__ __forceinline__ void top2_upd(float v, int i, float& v1, int& i1, float& v2) {
    if (v > v1) { v2 = v1; v1 = v; i1 = i; }
    else        { v2 = fmaxf(v2, v); }
}

// staging for one 32-K step of the 256x256 tile (see r6 comments).
__device__ __forceinline__ void stage_step(const _Float16* __restrict__ Xh,
                                           const _Float16* __restrict__ Eh,
                                           _Float16* dst, int split, int rowBase,
                                           int S, int r0, int ldsOff, int colOff) {
    const int ntB = split * 4096 + (S >> 4) * 256;
    const int col = ((S & 15) << 5) + colOff;
    gld16(Eh + (size_t)(ntB + r0)           * DIM + col, dst + ldsOff);
    gld16(Eh + (size_t)(ntB + 128 + r0)     * DIM + col, dst + 4096 + ldsOff);
    gld16(Xh + (size_t)(rowBase + r0)       * DIM + col, dst + 8192 + ldsOff);
    gld16(Xh + (size_t)(rowBase + 128 + r0) * DIM + col, dst + 12288 + ldsOff);
}

// one ks half-step's register fragments: 4 A (codes) + 2 B (rows) = 24 VGPR.
struct FragSet { half8 a0, a1, a2, a3, b0, b1; };

__device__ __forceinline__ void read_frags(const _Float16* __restrict__ B, int ks,
                                           int wc, int c, int h, int Pc, int wrr,
                                           FragSet& f) {
    const int so = (((ks << 1) + h) ^ Pc) << 3;
    f.a0 = *(const half8*)&B[(wc * 128 +  0 + c) * 32 + so];
    f.a1 = *(const half8*)&B[(wc * 128 + 32 + c) * 32 + so];
    f.a2 = *(const half8*)&B[(wc * 128 + 64 + c) * 32 + so];
    f.a3 = *(const half8*)&B[(wc * 128 + 96 + c) * 32 + so];
    f.b0 = *(const half8*)&B[8192 + (wrr * 64 +  0 + c) * 32 + so];
    f.b1 = *(const half8*)&B[8192 + (wrr * 64 + 32 + c) * 32 + so];
}

__device__ __forceinline__ void mfma8(const FragSet& f, floatx16 acc[4][2]) {
    acc[0][0] = __builtin_amdgcn_mfma_f32_32x32x16_f16(f.a0, f.b0, acc[0][0], 0, 0, 0);
    acc[1][0] = __builtin_amdgcn_mfma_f32_32x32x16_f16(f.a1, f.b0, acc[1][0], 0, 0, 0);
    acc[2][0] = __builtin_amdgcn_mfma_f32_32x32x16_f16(f.a2, f.b0, acc[2][0], 0, 0, 0);
    acc[3][0] = __builtin_amdgcn_mfma_f32_32x32x16_f16(f.a3, f.b0, acc[3][0], 0, 0, 0);
    acc[0][1] = __builtin_amdgcn_mfma_f32_32x32x16_f16(f.a0, f.b1, acc[0][1], 0, 0, 0);
    acc[1][1] = __builtin_amdgcn_mfma_f32_32x32x16_f16(f.a1, f.b1, acc[1][1], 0, 0, 0);
    acc[2][1] = __builtin_amdgcn_mfma_f32_32x32x16_f16(f.a2, f.b1, acc[2][1], 0, 0, 0);
    acc[3][1] = __builtin_amdgcn_mfma_f32_32x32x16_f16(f.a3, f.b1, acc[3][1], 0, 0, 0);
}

// hi-only f16 screening pass — 8-wave 256x256 + cross-barrier register
// prefetch. Step S's frags are read during step S-1 (the one transform the
// compiler cannot do itself: barriers fence its LDS scheduling), so each
// step's MFMA cluster starts on already-delivered registers. Tail-of-step
// counted vmcnt(4) + raw s_barrier (minimal fences, m141 lesson); all
// ds_reads are plain C++ loads so the compiler's precise counted-lgkm
// tracking keeps prefetch reads in flight under the MFMAs. Frag rotation
// fcur<-fnext via SSA (no dynamic indexing, rule #20).
__launch_bounds__(512, 2)
__global__ void k_hi(const _Float16* __restrict__ Xh, const _Float16* __restrict__ Eh,
                     float* __restrict__ sV1, float* __restrict__ sV2,
                     unsigned short* __restrict__ sI1) {
    __shared__ __align__(16) _Float16 lds[4 * 16384];   // 128 KiB, 4 buffers
    __shared__ float mV[256][2], mV2[256][2];
    __shared__ int   mI[256][2];

    const int tid  = threadIdx.x;
    const int w    = tid >> 6;
    const int lane = tid & 63;
    const int wc  = w & 1;        // code half: 0 -> codes 0-127, 1 -> 128-255
    const int wrr = w >> 1;       // row quarter: rows wrr*64 .. +63
    const int c = lane & 31, h = lane >> 5;
    const int rowBase = blockIdx.x * 256;
    const int split   = blockIdx.y;

    // staging lane geometry: 4 lanes/row, 128 rows per gld16 call
    const int r0   = tid >> 2;                           // 0..127
    const int slot = tid & 3;
    const int Ps   = ((tid >> 2) ^ (tid >> 4)) & 3;      // P(r0), m-independent
    const int colOff = (slot ^ Ps) * 8;                  // pre-swizzled source col
    const int ldsOff = r0 * 32 + slot * 8;               // linear dest (lane*16B per wave)

    // read-side swizzle: slot = g ^ P(row); P(row)=Pc for all frag rows
    const int Pc = (c ^ (c >> 2)) & 3;

    float v1a = -1e30f, v2a = -1e30f, v1b = -1e30f, v2b = -1e30f;
    int i1a = 0, i1b = 0;

    // prologue: stage steps 0,1,2; confirm bufs 0,1 (vmcnt(4) leaves only
    // buf2's 4 loads outstanding); pre-read F(0,0).
    stage_step(Xh, Eh, &lds[0],     split, rowBase, 0, r0, ldsOff, colOff);
    stage_step(Xh, Eh, &lds[16384], split, rowBase, 1, r0, ldsOff, colOff);
    stage_step(Xh, Eh, &lds[32768], split, rowBase, 2, r0, ldsOff, colOff);
    asm volatile("s_waitcnt vmcnt(4)" ::: "memory");
    __builtin_amdgcn_s_barrier();

    FragSet fcur, fmid, fnext;
    read_frags(&lds[0], 0, wc, c, h, Pc, wrr, fcur);

    for (int nt = 0; nt < 16; ++nt) {
        const int ntBase = split * 4096 + nt * 256;
        floatx16 acc[4][2];
        #pragma unroll
        for (int i = 0; i < 4; ++i)
            #pragma unroll
            for (int j = 0; j < 2; ++j)
                #pragma unroll
                for (int r = 0; r < 16; ++r) acc[i][j][r] = 0.f;

        #pragma unroll
        for (int k = 0; k < 16; ++k) {
            const int S = nt * 16 + k;          // nt*16 ≡ 0 mod 4 -> buf idx = f(k) compile-time
            // prefetch next step's ks=0 frags from buf(S+1) (confirmed by
            // the previous tail vmcnt+barrier), issue next-next-next stage,
            // read this step's ks=1 frags — all hidden under the MFMAs.
            read_frags(&lds[((k + 1) & 3) * 16384], 0, wc, c, h, Pc, wrr, fnext);
            stage_step(Xh, Eh, &lds[((k + 3) & 3) * 16384], split, rowBase,
                       (S + 3) & 255, r0, ldsOff, colOff);
            read_frags(&lds[(k & 3) * 16384], 1, wc, c, h, Pc, wrr, fmid);
            __builtin_amdgcn_s_setprio(1);
            mfma8(fcur, acc);                    // F(S,0): delivered (read step S-1)
            mfma8(fmid, acc);                    // F(S,1): auto counted-lgkm wait
            __builtin_amdgcn_s_setprio(0);
            fcur = fnext;
            // tail sync for step S+1: own stage(S-1) loads (= buf(S+2)) landed,
            // then block-wide barrier => buf(S+2) globally ready; also fences
            // the stage(S+1)->buf(S) overwrite against this step's reads.
            asm volatile("s_waitcnt vmcnt(4)" ::: "memory");
            __builtin_amdgcn_s_barrier();
        }
        #pragma unroll
        for (int r = 0; r < 16; ++r) {
            const int codeSub = (r & 3) + ((r >> 2) << 3) + (h << 2);
            #pragma unroll
            for (int i = 0; i < 4; ++i) {
                const int code = ntBase + wc * 128 + i * 32 + codeSub;
                top2_upd(acc[i][0][r], code, v1a, i1a, v2a);
                top2_upd(acc[i][1][r], code, v1b, i1b, v2b);
            }
        }
    }

    // merge h-halves (disjoint code sets, same row)
    {
        float ov1 = __shfl_xor(v1a, 32); int oi1 = __shfl_xor(i1a, 32); float ov2 = __shfl_xor(v2a, 32);
        if (ov1 > v1a) { v2a = fmaxf(v1a, ov2); v1a = ov1; i1a = oi1; }
        else if (ov1 == v1a) { v2a = v1a; if (oi1 < i1a) i1a = oi1; }
        else { v2a = fmaxf(v2a, ov1); }
        ov1 = __shfl_xor(v1b, 32); oi1 = __shfl_xor(i1b, 32); ov2 = __shfl_xor(v2b, 32);
        if (ov1 > v1b) { v2b = fmaxf(v1b, ov2); v1b = ov1; i1b = oi1; }
        else if (ov1 == v1b) { v2b = v1b; if (oi1 < i1b) i1b = oi1; }
        else { v2b = fmaxf(v2b, ov1); }
    }
    if (h == 0) {
        const int rA = wrr * 64 + c;
        mV[rA][wc] = v1a; mV2[rA][wc] = v2a; mI[rA][wc] = i1a;
        mV[rA + 32][wc] = v1b; mV2[rA + 32][wc] = v2b; mI[rA + 32][wc] = i1b;
    }
    __syncthreads();
    if (tid < 256) {
        float v1 = mV[tid][0], v2 = mV2[tid][0]; int i1 = mI[tid][0];
        float ov1 = mV[tid][1], ov2 = mV2[tid][1]; int oi1 = mI[tid][1];
        if (ov1 > v1) { v2 = fmaxf(v1, ov2); v1 = ov1; i1 = oi1; }
        else if (ov1 == v1) { v2 = v1; if (oi1 < i1) i1 = oi1; }
        else { v2 = fmaxf(v2, ov1); }
        const int n = rowBase + tid;
        sV1[split * NROWS + n] = v1;
        sV2[split * NROWS + n] = v2;
        sI1[split * NROWS + n] = (unsigned short)i1;
    }
}

__global__ void k_top2_merge(const float* __restrict__ sV1, const float* __restrict__ sV2,
                             const unsigned short* __restrict__ sI1,
                             float* __restrict__ outIdx, int* __restrict__ list,
                             int* __restrict__ flagCnt) {
    const int n = blockIdx.x * 256 + threadIdx.x;
    float a1 = sV1[n], a2 = sV2[n]; int ai = sI1[n];
    float b1 = sV1[NROWS + n], b2 = sV2[NROWS + n]; int bi = sI1[NROWS + n];
    float best, run; int bidx;
    if (b1 > a1) { best = b1; bidx = bi; run = fmaxf(a1, b2); }
    else         { best = a1; bidx = ai; run = fmaxf(a2, b1); }
    outIdx[n] = (float)bidx;
    if (best - run < MARGIN) {
        int p = atomicAdd(flagCnt, 1);
        list[p] = n;
    }
}

__device__ __forceinline__ unsigned long long encodeKey(float v, int idx) {
    unsigned u = __float_as_uint(v);
    u = (u & 0x80000000u) ? ~u : (u | 0x80000000u);
    return ((unsigned long long)u << 32) | (unsigned)(0xFFFFFFFFu - (unsigned)idx);
}

// dual-precision rescore of flagged rows (r2-identical numerics).
__launch_bounds__(256, 2)
__global__ void k_rescore(const _Float16* __restrict__ Xh, const _Float16* __restrict__ Xl,
                          const _Float16* __restrict__ Eh, const _Float16* __restrict__ El,
                          const int* __restrict__ list, const int* __restrict__ flagCnt,
                          unsigned long long* __restrict__ rkey) {
    const int cnt = *flagCnt;
    const int t = blockIdx.x & 255;
    const int s = blockIdx.x >> 8;
    if (t * 128 >= cnt) return;

    __shared__ __align__(16) _Float16 lds[32768];  // Eh|El|Xh|Xl, 8192 halves each
    __shared__ float mV[128][2];
    __shared__ int   mI[128][2];

    const int tid  = threadIdx.x;
    const int w    = tid >> 6;
    const int lane = tid & 63;
    const int wc = w & 1, wr = w >> 1;
    const int c = lane & 31, h = lane >> 5;
    const int sr = lane >> 3;
    const int sg = (lane & 7) ^ (sr & 7);
    const int rowA = wc * 64 + c;
    const int rowB = wr * 64 + c;
    const int cx = c & 7;

    int rows_j[4];
    #pragma unroll
    for (int j = 0; j < 4; ++j) {
        const int slot = t * 128 + w * 32 + j * 8 + sr;
        rows_j[j] = (slot < cnt) ? list[slot] : 0;
    }

    float best0 = -1e30f, best1 = -1e30f;
    int bi0 = 0, bi1 = 0;
    const float SC = 1.0f / 4096.0f;

    for (int nt = 0; nt < 4; ++nt) {
        const int ntBase = s * 512 + nt * 128;

        floatx16 accH00, accH01, accH10, accH11, accC00, accC01, accC10, accC11;
        #pragma unroll
        for (int r = 0; r < 16; ++r) {
            accH00[r] = 0.f; accH01[r] = 0.f; accH10[r] = 0.f; accH11[r] = 0.f;
            accC00[r] = 0.f; accC01[r] = 0.f; accC10[r] = 0.f; accC11[r] = 0.f;
        }

        for (int chunk = 0; chunk < 8; ++chunk) {
            const int kt = chunk * 64;
            #pragma unroll
            for (int j = 0; j < 4; ++j) {
                const int rl = w * 32 + j * 8 + sr;
                const size_t gE = (size_t)(ntBase + rl) * DIM + kt + sg * 8;
                const size_t gX = (size_t)rows_j[j] * DIM + kt + sg * 8;
                _Float16* dBase = &lds[(w * 32 + j * 8) * 64];
                gld16(Eh + gE, dBase);
                gld16(El + gE, dBase + 8192);
                gld16(Xh + gX, dBase + 16384);
                gld16(Xl + gX, dBase + 24576);
            }
            __syncthreads();
            #pragma unroll
            for (int ks = 0; ks < 4; ++ks) {
                const int so = ((ks * 2 + h) ^ cx) * 8;
                const half8 ah0 = *(const half8*)&lds[rowA * 64 + so];
                const half8 ah1 = *(const half8*)&lds[(rowA + 32) * 64 + so];
                const half8 al0 = *(const half8*)&lds[8192 + rowA * 64 + so];
                const half8 al1 = *(const half8*)&lds[8192 + (rowA + 32) * 64 + so];
                const half8 bh0 = *(const half8*)&lds[16384 + rowB * 64 + so];
                const half8 bh1 = *(const half8*)&lds[16384 + (rowB + 32) * 64 + so];
                const half8 bl0 = *(const half8*)&lds[24576 + rowB * 64 + so];
                const half8 bl1 = *(const half8*)&lds[24576 + (rowB + 32) * 64 + so];

                accH00 = __builtin_amdgcn_mfma_f32_32x32x16_f16(ah0, bh0, accH00, 0, 0, 0);
                accC00 = __builtin_amdgcn_mfma_f32_32x32x16_f16(ah0, bl0, accC00, 0, 0, 0);
                accC00 = __builtin_amdgcn_mfma_f32_32x32x16_f16(al0, bh0, accC00, 0, 0, 0);

                accH01 = __builtin_amdgcn_mfma_f32_32x32x16_f16(ah0, bh1, accH01, 0, 0, 0);
                accC01 = __builtin_amdgcn_mfma_f32_32x32x16_f16(ah0, bl1, accC01, 0, 0, 0);
                accC01 = __builtin_amdgcn_mfma_f32_32x32x16_f16(al0, bh1, accC01, 0, 0, 0);

                accH10 = __builtin_amdgcn_mfma_f32_32x32x16_f16(ah1, bh0, accH10, 0, 0, 0);
                accC10 = __builtin_amdgcn_mfma_f32_32x32x16_f16(ah1, bl0, accC10, 0, 0, 0);
                accC10 = __builtin_amdgcn_mfma_f32_32x32x16_f16(al1, bh0, accC10, 0, 0, 0);

                accH11 = __builtin_amdgcn_mfma_f32_32x32x16_f16(ah1, bh1, accH11, 0, 0, 0);
                accC11 = __builtin_amdgcn_mfma_f32_32x32x16_f16(ah1, bl1, accC11, 0, 0, 0);
                accC11 = __builtin_amdgcn_mfma_f32_32x32x16_f16(al1, bh1, accC11, 0, 0, 0);
            }
            __syncthreads();
        }

        #pragma unroll
        for (int r = 0; r < 16; ++r) {
            const int codeSub = (r & 3) + ((r >> 2) << 3) + (h << 2);
            const int code0 = ntBase + wc * 64 + codeSub;
            const int code1 = code0 + 32;
            float v;
            v = fmaf(accC00[r], SC, accH00[r]);
            if (v > best0 || (v == best0 && code0 < bi0)) { best0 = v; bi0 = code0; }
            v = fmaf(accC10[r], SC, accH10[r]);
            if (v > best0 || (v == best0 && code1 < bi0)) { best0 = v; bi0 = code1; }
            v = fmaf(accC01[r], SC, accH01[r]);
            if (v > best1 || (v == best1 && code0 < bi1)) { best1 = v; bi1 = code0; }
            v = fmaf(accC11[r], SC, accH11[r]);
            if (v > best1 || (v == best1 && code1 < bi1)) { best1 = v; bi1 = code1; }
        }
    }

    {
        float ov = __shfl_xor(best0, 32); int oi = __shfl_xor(bi0, 32);
        if (ov > best0 || (ov == best0 && oi < bi0)) { best0 = ov; bi0 = oi; }
        ov = __shfl_xor(best1, 32); oi = __shfl_xor(bi1, 32);
        if (ov > best1 || (ov == best1 && oi < bi1)) { best1 = ov; bi1 = oi; }
    }
    if (h == 0) {
        mV[rowB][wc] = best0;      mI[rowB][wc] = bi0;
        mV[rowB + 32][wc] = best1; mI[rowB + 32][wc] = bi1;
    }
    __syncthreads();
    if (tid < 128) {
        const int slot = t * 128 + tid;
        if (slot < cnt) {
            float v0 = mV[tid][0]; int i0 = mI[tid][0];
            float v1 = mV[tid][1]; int i1 = mI[tid][1];
            float bv; int bidx;
            if (v1 > v0 || (v1 == v0 && i1 < i0)) { bv = v1; bidx = i1; }
            else                                  { bv = v0; bidx = i0; }
            atomicMax(&rkey[list[slot]], encodeKey(bv, bidx));
        }
    }
}

__global__ void k_rescore_merge(const unsigned long long* __restrict__ rkey,
                                const int* __restrict__ list, const int* __restrict__ flagCnt,
                                float* __restrict__ outIdx) {
    const int slot = blockIdx.x * 256 + threadIdx.x;
    if (slot < *flagCnt) {
        const int row = list[slot];
        const unsigned long long key = rkey[row];
        const int code = (int)(0xFFFFFFFFu - (unsigned)(key & 0xFFFFFFFFull));
        outIdx[row] = (float)code;
    }
}

__global__ void k_hist(const float* __restrict__ outIdx, int* __restrict__ cntI) {
    const int n = blockIdx.x * 256 + threadIdx.x;
    atomicAdd(&cntI[(int)outIdx[n]], 1);
}

// grid-strided gather + loss: 2048 blocks x 256 threads, 8 float4-groups/thread.
__global__ void k_gather_loss(const float* __restrict__ X, const _Float16* __restrict__ Eh,
                              const _Float16* __restrict__ El, const float* __restrict__ outIdx,
                              float* __restrict__ qst, float* __restrict__ lossAcc) {
    const float SC = 1.0f / 4096.0f;
    float acc = 0.f;
    #pragma unroll
    for (int it = 0; it < 8; ++it) {
        const int e = (it * 2048 + blockIdx.x) * 256 + threadIdx.x;   // float4 index
        const int row = e >> 7;                                       // 128 float4 per row
        const int col = (e & 127) * 4;
        const int k = (int)outIdx[row];
        const float4 x = ((const float4*)X)[e];
        const half4v eh = *(const half4v*)&Eh[(size_t)k * DIM + col];
        const half4v el = *(const half4v*)&El[(size_t)k * DIM + col];
        const float q0 = (float)eh.x + (float)el.x * SC;
        const float q1 = (float)eh.y + (float)el.y * SC;
        const float q2 = (float)eh.z + (float)el.z * SC;
        const float q3 = (float)eh.w + (float)el.w * SC;
        const float d0 = q0 - x.x, d1 = q1 - x.y, d2 = q2 - x.z, d3 = q3 - x.w;
        float4 o; o.x = x.x + d0; o.y = x.y + d1; o.z = x.z + d2; o.w = x.w + d3;
        ((float4*)qst)[e] = o;
        acc += d0 * d0 + d1 * d1 + d2 * d2 + d3 * d3;
    }
    const float ls = block_sum_256(acc);
    if (threadIdx.x == 0) atomicAdd(lossAcc, ls);
}

__global__ void k_cs_pre(const float* __restrict__ emacs, const int* __restrict__ cntI,
                         float* __restrict__ pre, float* __restrict__ nsum) {
    const int k = blockIdx.x * 256 + threadIdx.x;
    float p = emacs[k] * DECAYF + OMDF * (float)cntI[k];
    pre[k] = p;
    float s = block_sum_256(p);
    if (threadIdx.x == 0) atomicAdd(nsum, s);
}

__global__ void k_cs_final(const float* __restrict__ pre, const float* __restrict__ nsum,
                           float* __restrict__ outCS, float* __restrict__ csfin,
                           const float* __restrict__ lossAcc, float* __restrict__ outLoss) {
    const int k = blockIdx.x * 256 + threadIdx.x;
    float n = *nsum;
    float c = (pre[k] + EPSF) / (n + (float)KCODE * EPSF) * n;
    outCS[k] = c;
    csfin[k] = c;
    if (k == 0) *outLoss = COMMITF * (*lossAcc) / (float)(NROWS * DIM);
}

__global__ void k_scan(const int* __restrict__ cntI, int* __restrict__ offs) {
    __shared__ int ps[1024];
    const int t = threadIdx.x;
    int loc[8], pref[8], s = 0;
    #pragma unroll
    for (int j = 0; j < 8; ++j) { loc[j] = cntI[t * 8 + j]; pref[j] = s; s += loc[j]; }
    ps[t] = s;
    __syncthreads();
    for (int d = 1; d < 1024; d <<= 1) {
        int x = (t >= d) ? ps[t - d] : 0;
        __syncthreads();
        ps[t] += x;
        __syncthreads();
    }
    const int base = ps[t] - s;
    #pragma unroll
    for (int j = 0; j < 8; ++j) offs[t * 8 + j] = base + pref[j];
}

__global__ void k_bin(const float* __restrict__ outIdx, const int* __restrict__ offs,
                      int* __restrict__ cursor, int* __restrict__ perm) {
    const int n = blockIdx.x * 256 + threadIdx.x;
    const int k = (int)outIdx[n];
    const int pos = offs[k] + atomicAdd(&cursor[k], 1);
    perm[pos] = n;
}

// one block per code: dw accumulation + EMA weight + embedding, fused.
__global__ void k_dw_fused(const float* __restrict__ X, const float* __restrict__ inv_in,
                           const int* __restrict__ perm, const int* __restrict__ offs,
                           const int* __restrict__ cntI, const float* __restrict__ emaw,
                           const float* __restrict__ csfin,
                           float* __restrict__ outW, float* __restrict__ outE) {
    const int k = blockIdx.x;
    const int t = threadIdx.x;
    const int c = cntI[k];
    const int base = offs[k];
    float a0 = 0.f, a1 = 0.f;
    for (int i = 0; i < c; ++i) {
        const int row = perm[base + i];
        const float iv = inv_in[row];
        const float2 x = *(const float2*)&X[(size_t)row * DIM + t * 2];
        a0 = fmaf(x.x, iv, a0);
        a1 = fmaf(x.y, iv, a1);
    }
    const float2 w2 = *(const float2*)&emaw[(size_t)k * DIM + t * 2];
    const float w0 = w2.x * DECAYF + OMDF * a0;
    const float w1 = w2.y * DECAYF + OMDF * a1;
    float2 ow; ow.x = w0; ow.y = w1;
    *(float2*)&outW[(size_t)k * DIM + t * 2] = ow;
    const float cs = fmaxf(csfin[k], EPSF);
    float2 oe; oe.x = w0 / cs; oe.y = w1 / cs;
    *(float2*)&outE[(size_t)k * DIM + t * 2] = oe;
}

extern "C" void kernel_launch(void* const* d_in, const int* in_sizes, int n_in,
                              void* d_out, int out_size, void* d_ws, size_t ws_size,
                              hipStream_t stream) {
    const float* inputs    = (const float*)d_in[0];
    const float* embedding = (const float*)d_in[1];
    const float* emacs     = (const float*)d_in[2];
    const float* emaw      = (const float*)d_in[3];
    float* out = (float*)d_out;
    float* ws  = (float*)d_ws;

    float* inv_in  = ws;
    float* sV1     = ws + 32768;
    float* sV2     = ws + 98304;
    unsigned short* sI1 = (unsigned short*)(ws + 163840);
    int*   list    = (int*)(ws + 196608);
    int*   flagCnt = (int*)(ws + 229376);
    float* inv_emb = ws + 229440;            // overlays Xh head, dead before X norm_split
    _Float16* Xh   = (_Float16*)(ws + 229440);
    _Float16* Xl   = (_Float16*)(ws + 8618048);
    _Float16* Eh   = (_Float16*)(ws + 17006656);
    _Float16* El   = (_Float16*)(ws + 19103808);
    // overlays valid after k_top2_merge:
    unsigned long long* rkey = (unsigned long long*)(ws + 32768);
    int*   cntI    = (int*)(ws + 98304);
    int*   cursor  = (int*)(ws + 106496);
    float* lossAcc = ws + 114688;
    float* nsum    = ws + 114689;
    float* pre     = ws + 114692;
    float* csfin   = ws + 122884;
    int*   offs    = (int*)(ws + 131076);
    int*   perm    = (int*)(ws + 139268);

    float* outQst  = out;
    float* outLoss = out + 16777216;
    float* outIdx  = out + 16777217;
    float* outCS   = out + 16809985;
    float* outW    = out + 16818177;
    float* outE    = out + 21012481;

    hipMemsetAsync(flagCnt, 0, sizeof(int), stream);
    // fused norm+split: E first (its inv scratch overlays Xh head, dead after),
    // then X (clobbers that scratch; inv_in is kept for k_dw_fused).
    k_norm_split<<<KCODE / 4, 256, 0, stream>>>(embedding, inv_emb, Eh, El);
    k_norm_split<<<NROWS / 4, 256, 0, stream>>>(inputs, inv_in, Xh, Xl);
    k_hi<<<dim3(NROWS / 256, 2), 512, 0, stream>>>(Xh, Eh, sV1, sV2, sI1);
    k_top2_merge<<<NROWS / 256, 256, 0, stream>>>(sV1, sV2, sI1, outIdx, list, flagCnt);
    // zero overlays: rkey(65536) + cntI(8192) + cursor(8192) + lossAcc + nsum
    hipMemsetAsync(ws + 32768, 0, (size_t)81922 * sizeof(float), stream);
    k_rescore<<<4096, 256, 0, stream>>>(Xh, Xl, Eh, El, list, flagCnt, rkey);
    k_rescore_merge<<<NROWS / 256, 256, 0, stream>>>(rkey, list, flagCnt, outIdx);
    k_hist<<<NROWS / 256, 256, 0, stream>>>(outIdx, cntI);
    k_gather_loss<<<2048, 256, 0, stream>>>(inputs, Eh, El, outIdx, outQst, lossAcc);
    k_cs_pre<<<KCODE / 256, 256, 0, stream>>>(emacs, cntI, pre, nsum);
    k_cs_final<<<KCODE / 256, 256, 0, stream>>>(pre, nsum, outCS, csfin, lossAcc, outLoss);
    k_scan<<<1, 1024, 0, stream>>>(cntI, offs);
    k_bin<<<NROWS / 256, 256, 0, stream>>>(outIdx, offs, cursor, perm);
    k_dw_fused<<<KCODE, 256, 0, stream>>>(inputs, inv_in, perm, offs, cntI, emaw, csfin,
                                          outW, outE);
}

// Round 13
// 771.992 us; speedup vs baseline: 1.0076x; 1.0076x over previous
//
#include <hip/hip_runtime.h>
#include <math.h>

#define NROWS 32768
#define DIM   512
#define KCODE 8192
#define DECAYF 0.99f
#define OMDF   0.01f
#define EPSF   1e-5f
#define COMMITF 0.25f
#define MARGIN 8e-4f

typedef _Float16 half8 __attribute__((ext_vector_type(8)));
typedef _Float16 half4v __attribute__((ext_vector_type(4)));
typedef _Float16 half2v __attribute__((ext_vector_type(2)));
typedef float floatx16 __attribute__((ext_vector_type(16)));

// ws layout: see round-3 comment (unchanged).

__device__ __forceinline__ float block_sum_256(float v) {
    __shared__ float sm[4];
    int lane = threadIdx.x & 63, wave = threadIdx.x >> 6;
    #pragma unroll
    for (int off = 32; off; off >>= 1) v += __shfl_down(v, off);
    if (lane == 0) sm[wave] = v;
    __syncthreads();
    if (threadIdx.x == 0) v = sm[0] + sm[1] + sm[2] + sm[3];
    return v; // valid on thread 0 only
}

// fused rownorm + hi/lo split: one pass over src (saves a full re-read).
__global__ void k_norm_split(const float* __restrict__ src, float* __restrict__ inv,
                             _Float16* __restrict__ hi, _Float16* __restrict__ lo) {
    const int wave = threadIdx.x >> 6;
    const int lane = threadIdx.x & 63;
    const int row = blockIdx.x * 4 + wave;
    const float* p = src + (size_t)row * DIM;
    const float4 f1 = *(const float4*)&p[lane * 4];
    const float4 f2 = *(const float4*)&p[256 + lane * 4];
    float s = f1.x*f1.x + f1.y*f1.y + f1.z*f1.z + f1.w*f1.w
            + f2.x*f2.x + f2.y*f2.y + f2.z*f2.z + f2.w*f2.w;
    #pragma unroll
    for (int off = 32; off; off >>= 1) s += __shfl_down(s, off);
    const float iv = __shfl(1.0f / fmaxf(sqrtf(s), 1e-12f), 0);
    if (lane == 0) inv[row] = iv;

    {
        const float n0 = f1.x * iv, n1 = f1.y * iv, n2 = f1.z * iv, n3 = f1.w * iv;
        const _Float16 h0 = (_Float16)n0, h1 = (_Float16)n1, h2 = (_Float16)n2, h3 = (_Float16)n3;
        half4v hv = {h0, h1, h2, h3};
        *(half4v*)&hi[(size_t)row * DIM + lane * 4] = hv;
        half4v lv = {(_Float16)((n0 - (float)h0) * 4096.f),
                     (_Float16)((n1 - (float)h1) * 4096.f),
                     (_Float16)((n2 - (float)h2) * 4096.f),
                     (_Float16)((n3 - (float)h3) * 4096.f)};
        *(half4v*)&lo[(size_t)row * DIM + lane * 4] = lv;
    }
    {
        const float n0 = f2.x * iv, n1 = f2.y * iv, n2 = f2.z * iv, n3 = f2.w * iv;
        const _Float16 h0 = (_Float16)n0, h1 = (_Float16)n1, h2 = (_Float16)n2, h3 = (_Float16)n3;
        half4v hv = {h0, h1, h2, h3};
        *(half4v*)&hi[(size_t)row * DIM + 256 + lane * 4] = hv;
        half4v lv = {(_Float16)((n0 - (float)h0) * 4096.f),
                     (_Float16)((n1 - (float)h1) * 4096.f),
                     (_Float16)((n2 - (float)h2) * 4096.f),
                     (_Float16)((n3 - (float)h3) * 4096.f)};
        *(half4v*)&lo[(size_t)row * DIM + 256 + lane * 4] = lv;
    }
}

__device__ __forceinline__ void gld16(const _Float16* g, _Float16* l) {
    __builtin_amdgcn_global_load_lds(
        (const __attribute__((address_space(1))) void*)g,
        (__attribute__((address_space(3))) void*)l, 16, 0, 0);
}

__device__ __forceinline__ void top2_upd(float v, int i, float& v1, int& i1, float& v2) {
    if (v > v1) { v2 = v1; v1 = v; i1 = i; }
    else        { v2 = fmaxf(v2, v); }
}

// staging for one 32-K step of the 256x256 tile (see r6 comments).
__device__ __forceinline__ void stage_step(const _Float16* __restrict__ Xh,
                                           const _Float16* __restrict__ Eh,
                                           _Float16* dst, int split, int rowBase,
                                           int S, int r0, int ldsOff, int colOff) {
    const int ntB = split * 4096 + (S >> 4) * 256;
    const int col = ((S & 15) << 5) + colOff;
    gld16(Eh + (size_t)(ntB + r0)           * DIM + col, dst + ldsOff);
    gld16(Eh + (size_t)(ntB + 128 + r0)     * DIM + col, dst + 4096 + ldsOff);
    gld16(Xh + (size_t)(rowBase + r0)       * DIM + col, dst + 8192 + ldsOff);
    gld16(Xh + (size_t)(rowBase + 128 + r0) * DIM + col, dst + 12288 + ldsOff);
}

// one ks half-step's register fragments: 4 A (codes) + 2 B (rows) = 24 VGPR.
struct FragSet { half8 a0, a1, a2, a3, b0, b1; };

__device__ __forceinline__ void read_frags(const _Float16* __restrict__ B, int ks,
                                           int wc, int c, int h, int Pc, int wrr,
                                           FragSet& f) {
    const int so = (((ks << 1) + h) ^ Pc) << 3;
    f.a0 = *(const half8*)&B[(wc * 128 +  0 + c) * 32 + so];
    f.a1 = *(const half8*)&B[(wc * 128 + 32 + c) * 32 + so];
    f.a2 = *(const half8*)&B[(wc * 128 + 64 + c) * 32 + so];
    f.a3 = *(const half8*)&B[(wc * 128 + 96 + c) * 32 + so];
    f.b0 = *(const half8*)&B[8192 + (wrr * 64 +  0 + c) * 32 + so];
    f.b1 = *(const half8*)&B[8192 + (wrr * 64 + 32 + c) * 32 + so];
}

__device__ __forceinline__ void mfma8(const FragSet& f, floatx16 acc[4][2]) {
    acc[0][0] = __builtin_amdgcn_mfma_f32_32x32x16_f16(f.a0, f.b0, acc[0][0], 0, 0, 0);
    acc[1][0] = __builtin_amdgcn_mfma_f32_32x32x16_f16(f.a1, f.b0, acc[1][0], 0, 0, 0);
    acc[2][0] = __builtin_amdgcn_mfma_f32_32x32x16_f16(f.a2, f.b0, acc[2][0], 0, 0, 0);
    acc[3][0] = __builtin_amdgcn_mfma_f32_32x32x16_f16(f.a3, f.b0, acc[3][0], 0, 0, 0);
    acc[0][1] = __builtin_amdgcn_mfma_f32_32x32x16_f16(f.a0, f.b1, acc[0][1], 0, 0, 0);
    acc[1][1] = __builtin_amdgcn_mfma_f32_32x32x16_f16(f.a1, f.b1, acc[1][1], 0, 0, 0);
    acc[2][1] = __builtin_amdgcn_mfma_f32_32x32x16_f16(f.a2, f.b1, acc[2][1], 0, 0, 0);
    acc[3][1] = __builtin_amdgcn_mfma_f32_32x32x16_f16(f.a3, f.b1, acc[3][1], 0, 0, 0);
}

// hi-only f16 screening pass — 8-wave 256x256 + cross-barrier register
// prefetch. r10 showed this exact schedule is CORRECT but spilled at the
// 128-VGPR cap imposed by __launch_bounds__(512,2) (WRITE_SIZE 5->32MB,
// FETCH 2x). LDS (134KB) caps occupancy at 1 block/CU = 2 waves/SIMD
// where the HW VGPR budget is 256/wave — so relax the bound to (512,1):
// prefetch state (~+40 VGPR) fits in registers without occupancy loss.
__launch_bounds__(512, 1)
__global__ void k_hi(const _Float16* __restrict__ Xh, const _Float16* __restrict__ Eh,
                     float* __restrict__ sV1, float* __restrict__ sV2,
                     unsigned short* __restrict__ sI1) {
    __shared__ __align__(16) _Float16 lds[4 * 16384];   // 128 KiB, 4 buffers
    __shared__ float mV[256][2], mV2[256][2];
    __shared__ int   mI[256][2];

    const int tid  = threadIdx.x;
    const int w    = tid >> 6;
    const int lane = tid & 63;
    const int wc  = w & 1;        // code half: 0 -> codes 0-127, 1 -> 128-255
    const int wrr = w >> 1;       // row quarter: rows wrr*64 .. +63
    const int c = lane & 31, h = lane >> 5;
    const int rowBase = blockIdx.x * 256;
    const int split   = blockIdx.y;

    // staging lane geometry: 4 lanes/row, 128 rows per gld16 call
    const int r0   = tid >> 2;                           // 0..127
    const int slot = tid & 3;
    const int Ps   = ((tid >> 2) ^ (tid >> 4)) & 3;      // P(r0), m-independent
    const int colOff = (slot ^ Ps) * 8;                  // pre-swizzled source col
    const int ldsOff = r0 * 32 + slot * 8;               // linear dest (lane*16B per wave)

    // read-side swizzle: slot = g ^ P(row); P(row)=Pc for all frag rows
    const int Pc = (c ^ (c >> 2)) & 3;

    float v1a = -1e30f, v2a = -1e30f, v1b = -1e30f, v2b = -1e30f;
    int i1a = 0, i1b = 0;

    // prologue: stage steps 0,1,2; confirm bufs 0,1 (vmcnt(4) leaves only
    // buf2's 4 loads outstanding); pre-read F(0,0).
    stage_step(Xh, Eh, &lds[0],     split, rowBase, 0, r0, ldsOff, colOff);
    stage_step(Xh, Eh, &lds[16384], split, rowBase, 1, r0, ldsOff, colOff);
    stage_step(Xh, Eh, &lds[32768], split, rowBase, 2, r0, ldsOff, colOff);
    asm volatile("s_waitcnt vmcnt(4)" ::: "memory");
    __builtin_amdgcn_s_barrier();

    FragSet fcur, fmid, fnext;
    read_frags(&lds[0], 0, wc, c, h, Pc, wrr, fcur);

    for (int nt = 0; nt < 16; ++nt) {
        const int ntBase = split * 4096 + nt * 256;
        floatx16 acc[4][2];
        #pragma unroll
        for (int i = 0; i < 4; ++i)
            #pragma unroll
            for (int j = 0; j < 2; ++j)
                #pragma unroll
                for (int r = 0; r < 16; ++r) acc[i][j][r] = 0.f;

        #pragma unroll
        for (int k = 0; k < 16; ++k) {
            const int S = nt * 16 + k;          // nt*16 ≡ 0 mod 4 -> buf idx = f(k) compile-time
            // prefetch next step's ks=0 frags from buf(S+1) (confirmed by
            // the previous tail vmcnt+barrier), issue next-next-next stage,
            // read this step's ks=1 frags — all hidden under the MFMAs.
            read_frags(&lds[((k + 1) & 3) * 16384], 0, wc, c, h, Pc, wrr, fnext);
            stage_step(Xh, Eh, &lds[((k + 3) & 3) * 16384], split, rowBase,
                       (S + 3) & 255, r0, ldsOff, colOff);
            read_frags(&lds[(k & 3) * 16384], 1, wc, c, h, Pc, wrr, fmid);
            __builtin_amdgcn_s_setprio(1);
            mfma8(fcur, acc);                    // F(S,0): delivered (read step S-1)
            mfma8(fmid, acc);                    // F(S,1): auto counted-lgkm wait
            __builtin_amdgcn_s_setprio(0);
            fcur = fnext;
            // tail sync for step S+1: own stage(S-1) loads (= buf(S+2)) landed,
            // then block-wide barrier => buf(S+2) globally ready; also fences
            // the stage(S+1)->buf(S) overwrite against this step's reads.
            asm volatile("s_waitcnt vmcnt(4)" ::: "memory");
            __builtin_amdgcn_s_barrier();
        }
        #pragma unroll
        for (int r = 0; r < 16; ++r) {
            const int codeSub = (r & 3) + ((r >> 2) << 3) + (h << 2);
            #pragma unroll
            for (int i = 0; i < 4; ++i) {
                const int code = ntBase + wc * 128 + i * 32 + codeSub;
                top2_upd(acc[i][0][r], code, v1a, i1a, v2a);
                top2_upd(acc[i][1][r], code, v1b, i1b, v2b);
            }
        }
    }

    // merge h-halves (disjoint code sets, same row)
    {
        float ov1 = __shfl_xor(v1a, 32); int oi1 = __shfl_xor(i1a, 32); float ov2 = __shfl_xor(v2a, 32);
        if (ov1 > v1a) { v2a = fmaxf(v1a, ov2); v1a = ov1; i1a = oi1; }
        else if (ov1 == v1a) { v2a = v1a; if (oi1 < i1a) i1a = oi1; }
        else { v2a = fmaxf(v2a, ov1); }
        ov1 = __shfl_xor(v1b, 32); oi1 = __shfl_xor(i1b, 32); ov2 = __shfl_xor(v2b, 32);
        if (ov1 > v1b) { v2b = fmaxf(v1b, ov2); v1b = ov1; i1b = oi1; }
        else if (ov1 == v1b) { v2b = v1b; if (oi1 < i1b) i1b = oi1; }
        else { v2b = fmaxf(v2b, ov1); }
    }
    if (h == 0) {
        const int rA = wrr * 64 + c;
        mV[rA][wc] = v1a; mV2[rA][wc] = v2a; mI[rA][wc] = i1a;
        mV[rA + 32][wc] = v1b; mV2[rA + 32][wc] = v2b; mI[rA + 32][wc] = i1b;
    }
    __syncthreads();
    if (tid < 256) {
        float v1 = mV[tid][0], v2 = mV2[tid][0]; int i1 = mI[tid][0];
        float ov1 = mV[tid][1], ov2 = mV2[tid][1]; int oi1 = mI[tid][1];
        if (ov1 > v1) { v2 = fmaxf(v1, ov2); v1 = ov1; i1 = oi1; }
        else if (ov1 == v1) { v2 = v1; if (oi1 < i1) i1 = oi1; }
        else { v2 = fmaxf(v2, ov1); }
        const int n = rowBase + tid;
        sV1[split * NROWS + n] = v1;
        sV2[split * NROWS + n] = v2;
        sI1[split * NROWS + n] = (unsigned short)i1;
    }
}

__global__ void k_top2_merge(const float* __restrict__ sV1, const float* __restrict__ sV2,
                             const unsigned short* __restrict__ sI1,
                             float* __restrict__ outIdx, int* __restrict__ list,
                             int* __restrict__ flagCnt) {
    const int n = blockIdx.x * 256 + threadIdx.x;
    float a1 = sV1[n], a2 = sV2[n]; int ai = sI1[n];
    float b1 = sV1[NROWS + n], b2 = sV2[NROWS + n]; int bi = sI1[NROWS + n];
    float best, run; int bidx;
    if (b1 > a1) { best = b1; bidx = bi; run = fmaxf(a1, b2); }
    else         { best = a1; bidx = ai; run = fmaxf(a2, b1); }
    outIdx[n] = (float)bidx;
    if (best - run < MARGIN) {
        int p = atomicAdd(flagCnt, 1);
        list[p] = n;
    }
}

__device__ __forceinline__ unsigned long long encodeKey(float v, int idx) {
    unsigned u = __float_as_uint(v);
    u = (u & 0x80000000u) ? ~u : (u | 0x80000000u);
    return ((unsigned long long)u << 32) | (unsigned)(0xFFFFFFFFu - (unsigned)idx);
}

// dual-precision rescore of flagged rows (r2-identical numerics).
__launch_bounds__(256, 2)
__global__ void k_rescore(const _Float16* __restrict__ Xh, const _Float16* __restrict__ Xl,
                          const _Float16* __restrict__ Eh, const _Float16* __restrict__ El,
                          const int* __restrict__ list, const int* __restrict__ flagCnt,
                          unsigned long long* __restrict__ rkey) {
    const int cnt = *flagCnt;
    const int t = blockIdx.x & 255;
    const int s = blockIdx.x >> 8;
    if (t * 128 >= cnt) return;

    __shared__ __align__(16) _Float16 lds[32768];  // Eh|El|Xh|Xl, 8192 halves each
    __shared__ float mV[128][2];
    __shared__ int   mI[128][2];

    const int tid  = threadIdx.x;
    const int w    = tid >> 6;
    const int lane = tid & 63;
    const int wc = w & 1, wr = w >> 1;
    const int c = lane & 31, h = lane >> 5;
    const int sr = lane >> 3;
    const int sg = (lane & 7) ^ (sr & 7);
    const int rowA = wc * 64 + c;
    const int rowB = wr * 64 + c;
    const int cx = c & 7;

    int rows_j[4];
    #pragma unroll
    for (int j = 0; j < 4; ++j) {
        const int slot = t * 128 + w * 32 + j * 8 + sr;
        rows_j[j] = (slot < cnt) ? list[slot] : 0;
    }

    float best0 = -1e30f, best1 = -1e30f;
    int bi0 = 0, bi1 = 0;
    const float SC = 1.0f / 4096.0f;

    for (int nt = 0; nt < 4; ++nt) {
        const int ntBase = s * 512 + nt * 128;

        floatx16 accH00, accH01, accH10, accH11, accC00, accC01, accC10, accC11;
        #pragma unroll
        for (int r = 0; r < 16; ++r) {
            accH00[r] = 0.f; accH01[r] = 0.f; accH10[r] = 0.f; accH11[r] = 0.f;
            accC00[r] = 0.f; accC01[r] = 0.f; accC10[r] = 0.f; accC11[r] = 0.f;
        }

        for (int chunk = 0; chunk < 8; ++chunk) {
            const int kt = chunk * 64;
            #pragma unroll
            for (int j = 0; j < 4; ++j) {
                const int rl = w * 32 + j * 8 + sr;
                const size_t gE = (size_t)(ntBase + rl) * DIM + kt + sg * 8;
                const size_t gX = (size_t)rows_j[j] * DIM + kt + sg * 8;
                _Float16* dBase = &lds[(w * 32 + j * 8) * 64];
                gld16(Eh + gE, dBase);
                gld16(El + gE, dBase + 8192);
                gld16(Xh + gX, dBase + 16384);
                gld16(Xl + gX, dBase + 24576);
            }
            __syncthreads();
            #pragma unroll
            for (int ks = 0; ks < 4; ++ks) {
                const int so = ((ks * 2 + h) ^ cx) * 8;
                const half8 ah0 = *(const half8*)&lds[rowA * 64 + so];
                const half8 ah1 = *(const half8*)&lds[(rowA + 32) * 64 + so];
                const half8 al0 = *(const half8*)&lds[8192 + rowA * 64 + so];
                const half8 al1 = *(const half8*)&lds[8192 + (rowA + 32) * 64 + so];
                const half8 bh0 = *(const half8*)&lds[16384 + rowB * 64 + so];
                const half8 bh1 = *(const half8*)&lds[16384 + (rowB + 32) * 64 + so];
                const half8 bl0 = *(const half8*)&lds[24576 + rowB * 64 + so];
                const half8 bl1 = *(const half8*)&lds[24576 + (rowB + 32) * 64 + so];

                accH00 = __builtin_amdgcn_mfma_f32_32x32x16_f16(ah0, bh0, accH00, 0, 0, 0);
                accC00 = __builtin_amdgcn_mfma_f32_32x32x16_f16(ah0, bl0, accC00, 0, 0, 0);
                accC00 = __builtin_amdgcn_mfma_f32_32x32x16_f16(al0, bh0, accC00, 0, 0, 0);

                accH01 = __builtin_amdgcn_mfma_f32_32x32x16_f16(ah0, bh1, accH01, 0, 0, 0);
                accC01 = __builtin_amdgcn_mfma_f32_32x32x16_f16(ah0, bl1, accC01, 0, 0, 0);
                accC01 = __builtin_amdgcn_mfma_f32_32x32x16_f16(al0, bh1, accC01, 0, 0, 0);

                accH10 = __builtin_amdgcn_mfma_f32_32x32x16_f16(ah1, bh0, accH10, 0, 0, 0);
                accC10 = __builtin_amdgcn_mfma_f32_32x32x16_f16(ah1, bl0, accC10, 0, 0, 0);
                accC10 = __builtin_amdgcn_mfma_f32_32x32x16_f16(al1, bh0, accC10, 0, 0, 0);

                accH11 = __builtin_amdgcn_mfma_f32_32x32x16_f16(ah1, bh1, accH11, 0, 0, 0);
                accC11 = __builtin_amdgcn_mfma_f32_32x32x16_f16(ah1, bl1, accC11, 0, 0, 0);
                accC11 = __builtin_amdgcn_mfma_f32_32x32x16_f16(al1, bh1, accC11, 0, 0, 0);
            }
            __syncthreads();
        }

        #pragma unroll
        for (int r = 0; r < 16; ++r) {
            const int codeSub = (r & 3) + ((r >> 2) << 3) + (h << 2);
            const int code0 = ntBase + wc * 64 + codeSub;
            const int code1 = code0 + 32;
            float v;
            v = fmaf(accC00[r], SC, accH00[r]);
            if (v > best0 || (v == best0 && code0 < bi0)) { best0 = v; bi0 = code0; }
            v = fmaf(accC10[r], SC, accH10[r]);
            if (v > best0 || (v == best0 && code1 < bi0)) { best0 = v; bi0 = code1; }
            v = fmaf(accC01[r], SC, accH01[r]);
            if (v > best1 || (v == best1 && code0 < bi1)) { best1 = v; bi1 = code0; }
            v = fmaf(accC11[r], SC, accH11[r]);
            if (v > best1 || (v == best1 && code1 < bi1)) { best1 = v; bi1 = code1; }
        }
    }

    {
        float ov = __shfl_xor(best0, 32); int oi = __shfl_xor(bi0, 32);
        if (ov > best0 || (ov == best0 && oi < bi0)) { best0 = ov; bi0 = oi; }
        ov = __shfl_xor(best1, 32); oi = __shfl_xor(bi1, 32);
        if (ov > best1 || (ov == best1 && oi < bi1)) { best1 = ov; bi1 = oi; }
    }
    if (h == 0) {
        mV[rowB][wc] = best0;      mI[rowB][wc] = bi0;
        mV[rowB + 32][wc] = best1; mI[rowB + 32][wc] = bi1;
    }
    __syncthreads();
    if (tid < 128) {
        const int slot = t * 128 + tid;
        if (slot < cnt) {
            float v0 = mV[tid][0]; int i0 = mI[tid][0];
            float v1 = mV[tid][1]; int i1 = mI[tid][1];
            float bv; int bidx;
            if (v1 > v0 || (v1 == v0 && i1 < i0)) { bv = v1; bidx = i1; }
            else                                  { bv = v0; bidx = i0; }
            atomicMax(&rkey[list[slot]], encodeKey(bv, bidx));
        }
    }
}

__global__ void k_rescore_merge(const unsigned long long* __restrict__ rkey,
                                const int* __restrict__ list, const int* __restrict__ flagCnt,
                                float* __restrict__ outIdx) {
    const int slot = blockIdx.x * 256 + threadIdx.x;
    if (slot < *flagCnt) {
        const int row = list[slot];
        const unsigned long long key = rkey[row];
        const int code = (int)(0xFFFFFFFFu - (unsigned)(key & 0xFFFFFFFFull));
        outIdx[row] = (float)code;
    }
}

__global__ void k_hist(const float* __restrict__ outIdx, int* __restrict__ cntI) {
    const int n = blockIdx.x * 256 + threadIdx.x;
    atomicAdd(&cntI[(int)outIdx[n]], 1);
}

// grid-strided gather + loss: 2048 blocks x 256 threads, 8 float4-groups/thread.
__global__ void k_gather_loss(const float* __restrict__ X, const _Float16* __restrict__ Eh,
                              const _Float16* __restrict__ El, const float* __restrict__ outIdx,
                              float* __restrict__ qst, float* __restrict__ lossAcc) {
    const float SC = 1.0f / 4096.0f;
    float acc = 0.f;
    #pragma unroll
    for (int it = 0; it < 8; ++it) {
        const int e = (it * 2048 + blockIdx.x) * 256 + threadIdx.x;   // float4 index
        const int row = e >> 7;                                       // 128 float4 per row
        const int col = (e & 127) * 4;
        const int k = (int)outIdx[row];
        const float4 x = ((const float4*)X)[e];
        const half4v eh = *(const half4v*)&Eh[(size_t)k * DIM + col];
        const half4v el = *(const half4v*)&El[(size_t)k * DIM + col];
        const float q0 = (float)eh.x + (float)el.x * SC;
        const float q1 = (float)eh.y + (float)el.y * SC;
        const float q2 = (float)eh.z + (float)el.z * SC;
        const float q3 = (float)eh.w + (float)el.w * SC;
        const float d0 = q0 - x.x, d1 = q1 - x.y, d2 = q2 - x.z, d3 = q3 - x.w;
        float4 o; o.x = x.x + d0; o.y = x.y + d1; o.z = x.z + d2; o.w = x.w + d3;
        ((float4*)qst)[e] = o;
        acc += d0 * d0 + d1 * d1 + d2 * d2 + d3 * d3;
    }
    const float ls = block_sum_256(acc);
    if (threadIdx.x == 0) atomicAdd(lossAcc, ls);
}

__global__ void k_cs_pre(const float* __restrict__ emacs, const int* __restrict__ cntI,
                         float* __restrict__ pre, float* __restrict__ nsum) {
    const int k = blockIdx.x * 256 + threadIdx.x;
    float p = emacs[k] * DECAYF + OMDF * (float)cntI[k];
    pre[k] = p;
    float s = block_sum_256(p);
    if (threadIdx.x == 0) atomicAdd(nsum, s);
}

__global__ void k_cs_final(const float* __restrict__ pre, const float* __restrict__ nsum,
                           float* __restrict__ outCS, float* __restrict__ csfin,
                           const float* __restrict__ lossAcc, float* __restrict__ outLoss) {
    const int k = blockIdx.x * 256 + threadIdx.x;
    float n = *nsum;
    float c = (pre[k] + EPSF) / (n + (float)KCODE * EPSF) * n;
    outCS[k] = c;
    csfin[k] = c;
    if (k == 0) *outLoss = COMMITF * (*lossAcc) / (float)(NROWS * DIM);
}

__global__ void k_scan(const int* __restrict__ cntI, int* __restrict__ offs) {
    __shared__ int ps[1024];
    const int t = threadIdx.x;
    int loc[8], pref[8], s = 0;
    #pragma unroll
    for (int j = 0; j < 8; ++j) { loc[j] = cntI[t * 8 + j]; pref[j] = s; s += loc[j]; }
    ps[t] = s;
    __syncthreads();
    for (int d = 1; d < 1024; d <<= 1) {
        int x = (t >= d) ? ps[t - d] : 0;
        __syncthreads();
        ps[t] += x;
        __syncthreads();
    }
    const int base = ps[t] - s;
    #pragma unroll
    for (int j = 0; j < 8; ++j) offs[t * 8 + j] = base + pref[j];
}

__global__ void k_bin(const float* __restrict__ outIdx, const int* __restrict__ offs,
                      int* __restrict__ cursor, int* __restrict__ perm) {
    const int n = blockIdx.x * 256 + threadIdx.x;
    const int k = (int)outIdx[n];
    const int pos = offs[k] + atomicAdd(&cursor[k], 1);
    perm[pos] = n;
}

// one block per code: dw accumulation + EMA weight + embedding, fused.
__global__ void k_dw_fused(const float* __restrict__ X, const float* __restrict__ inv_in,
                           const int* __restrict__ perm, const int* __restrict__ offs,
                           const int* __restrict__ cntI, const float* __restrict__ emaw,
                           const float* __restrict__ csfin,
                           float* __restrict__ outW, float* __restrict__ outE) {
    const int k = blockIdx.x;
    const int t = threadIdx.x;
    const int c = cntI[k];
    const int base = offs[k];
    float a0 = 0.f, a1 = 0.f;
    for (int i = 0; i < c; ++i) {
        const int row = perm[base + i];
        const float iv = inv_in[row];
        const float2 x = *(const float2*)&X[(size_t)row * DIM + t * 2];
        a0 = fmaf(x.x, iv, a0);
        a1 = fmaf(x.y, iv, a1);
    }
    const float2 w2 = *(const float2*)&emaw[(size_t)k * DIM + t * 2];
    const float w0 = w2.x * DECAYF + OMDF * a0;
    const float w1 = w2.y * DECAYF + OMDF * a1;
    float2 ow; ow.x = w0; ow.y = w1;
    *(float2*)&outW[(size_t)k * DIM + t * 2] = ow;
    const float cs = fmaxf(csfin[k], EPSF);
    float2 oe; oe.x = w0 / cs; oe.y = w1 / cs;
    *(float2*)&outE[(size_t)k * DIM + t * 2] = oe;
}

extern "C" void kernel_launch(void* const* d_in, const int* in_sizes, int n_in,
                              void* d_out, int out_size, void* d_ws, size_t ws_size,
                              hipStream_t stream) {
    const float* inputs    = (const float*)d_in[0];
    const float* embedding = (const float*)d_in[1];
    const float* emacs     = (const float*)d_in[2];
    const float* emaw      = (const float*)d_in[3];
    float* out = (float*)d_out;
    float* ws  = (float*)d_ws;

    float* inv_in  = ws;
    float* sV1     = ws + 32768;
    float* sV2     = ws + 98304;
    unsigned short* sI1 = (unsigned short*)(ws + 163840);
    int*   list    = (int*)(ws + 196608);
    int*   flagCnt = (int*)(ws + 229376);
    float* inv_emb = ws + 229440;            // overlays Xh head, dead before X norm_split
    _Float16* Xh   = (_Float16*)(ws + 229440);
    _Float16* Xl   = (_Float16*)(ws + 8618048);
    _Float16* Eh   = (_Float16*)(ws + 17006656);
    _Float16* El   = (_Float16*)(ws + 19103808);
    // overlays valid after k_top2_merge:
    unsigned long long* rkey = (unsigned long long*)(ws + 32768);
    int*   cntI    = (int*)(ws + 98304);
    int*   cursor  = (int*)(ws + 106496);
    float* lossAcc = ws + 114688;
    float* nsum    = ws + 114689;
    float* pre     = ws + 114692;
    float* csfin   = ws + 122884;
    int*   offs    = (int*)(ws + 131076);
    int*   perm    = (int*)(ws + 139268);

    float* outQst  = out;
    float* outLoss = out + 16777216;
    float* outIdx  = out + 16777217;
    float* outCS   = out + 16809985;
    float* outW    = out + 16818177;
    float* outE    = out + 21012481;

    hipMemsetAsync(flagCnt, 0, sizeof(int), stream);
    // fused norm+split: E first (its inv scratch overlays Xh head, dead after),
    // then X (clobbers that scratch; inv_in is kept for k_dw_fused).
    k_norm_split<<<KCODE / 4, 256, 0, stream>>>(embedding, inv_emb, Eh, El);
    k_norm_split<<<NROWS / 4, 256, 0, stream>>>(inputs, inv_in, Xh, Xl);
    k_hi<<<dim3(NROWS / 256, 2), 512, 0, stream>>>(Xh, Eh, sV1, sV2, sI1);
    k_top2_merge<<<NROWS / 256, 256, 0, stream>>>(sV1, sV2, sI1, outIdx, list, flagCnt);
    // zero overlays: rkey(65536) + cntI(8192) + cursor(8192) + lossAcc + nsum
    hipMemsetAsync(ws + 32768, 0, (size_t)81922 * sizeof(float), stream);
    k_rescore<<<4096, 256, 0, stream>>>(Xh, Xl, Eh, El, list, flagCnt, rkey);
    k_rescore_merge<<<NROWS / 256, 256, 0, stream>>>(rkey, list, flagCnt, outIdx);
    k_hist<<<NROWS / 256, 256, 0, stream>>>(outIdx, cntI);
    k_gather_loss<<<2048, 256, 0, stream>>>(inputs, Eh, El, outIdx, outQst, lossAcc);
    k_cs_pre<<<KCODE / 256, 256, 0, stream>>>(emacs, cntI, pre, nsum);
    k_cs_final<<<KCODE / 256, 256, 0, stream>>>(pre, nsum, outCS, csfin, lossAcc, outLoss);
    k_scan<<<1, 1024, 0, stream>>>(cntI, offs);
    k_bin<<<NROWS / 256, 256, 0, stream>>>(outIdx, offs, cursor, perm);
    k_dw_fused<<<KCODE, 256, 0, stream>>>(inputs, inv_in, perm, offs, cntI, emaw, csfin,
                                          outW, outE);
}

// Round 14
// 651.761 us; speedup vs baseline: 1.1935x; 1.1845x over previous
//
#include <hip/hip_runtime.h>
#include <math.h>

#define NROWS 32768
#define DIM   512
#define KCODE 8192
#define DECAYF 0.99f
#define OMDF   0.01f
#define EPSF   1e-5f
#define COMMITF 0.25f
#define MARGIN 8e-4f

typedef _Float16 half8 __attribute__((ext_vector_type(8)));
typedef _Float16 half4v __attribute__((ext_vector_type(4)));
typedef _Float16 half2v __attribute__((ext_vector_type(2)));
typedef float floatx16 __attribute__((ext_vector_type(16)));

// ws layout: see round-3 comment (unchanged).

__device__ __forceinline__ float block_sum_256(float v) {
    __shared__ float sm[4];
    int lane = threadIdx.x & 63, wave = threadIdx.x >> 6;
    #pragma unroll
    for (int off = 32; off; off >>= 1) v += __shfl_down(v, off);
    if (lane == 0) sm[wave] = v;
    __syncthreads();
    if (threadIdx.x == 0) v = sm[0] + sm[1] + sm[2] + sm[3];
    return v; // valid on thread 0 only
}

// fused rownorm + hi/lo split: one pass over src (saves a full re-read).
__global__ void k_norm_split(const float* __restrict__ src, float* __restrict__ inv,
                             _Float16* __restrict__ hi, _Float16* __restrict__ lo) {
    const int wave = threadIdx.x >> 6;
    const int lane = threadIdx.x & 63;
    const int row = blockIdx.x * 4 + wave;
    const float* p = src + (size_t)row * DIM;
    const float4 f1 = *(const float4*)&p[lane * 4];
    const float4 f2 = *(const float4*)&p[256 + lane * 4];
    float s = f1.x*f1.x + f1.y*f1.y + f1.z*f1.z + f1.w*f1.w
            + f2.x*f2.x + f2.y*f2.y + f2.z*f2.z + f2.w*f2.w;
    #pragma unroll
    for (int off = 32; off; off >>= 1) s += __shfl_down(s, off);
    const float iv = __shfl(1.0f / fmaxf(sqrtf(s), 1e-12f), 0);
    if (lane == 0) inv[row] = iv;

    {
        const float n0 = f1.x * iv, n1 = f1.y * iv, n2 = f1.z * iv, n3 = f1.w * iv;
        const _Float16 h0 = (_Float16)n0, h1 = (_Float16)n1, h2 = (_Float16)n2, h3 = (_Float16)n3;
        half4v hv = {h0, h1, h2, h3};
        *(half4v*)&hi[(size_t)row * DIM + lane * 4] = hv;
        half4v lv = {(_Float16)((n0 - (float)h0) * 4096.f),
                     (_Float16)((n1 - (float)h1) * 4096.f),
                     (_Float16)((n2 - (float)h2) * 4096.f),
                     (_Float16)((n3 - (float)h3) * 4096.f)};
        *(half4v*)&lo[(size_t)row * DIM + lane * 4] = lv;
    }
    {
        const float n0 = f2.x * iv, n1 = f2.y * iv, n2 = f2.z * iv, n3 = f2.w * iv;
        const _Float16 h0 = (_Float16)n0, h1 = (_Float16)n1, h2 = (_Float16)n2, h3 = (_Float16)n3;
        half4v hv = {h0, h1, h2, h3};
        *(half4v*)&hi[(size_t)row * DIM + 256 + lane * 4] = hv;
        half4v lv = {(_Float16)((n0 - (float)h0) * 4096.f),
                     (_Float16)((n1 - (float)h1) * 4096.f),
                     (_Float16)((n2 - (float)h2) * 4096.f),
                     (_Float16)((n3 - (float)h3) * 4096.f)};
        *(half4v*)&lo[(size_t)row * DIM + 256 + lane * 4] = lv;
    }
}

__device__ __forceinline__ void gld16(const _Float16* g, _Float16* l) {
    __builtin_amdgcn_global_load_lds(
        (const __attribute__((address_space(1))) void*)g,
        (__attribute__((address_space(3))) void*)l, 16, 0, 0);
}

__device__ __forceinline__ void top2_upd(float v, int i, float& v1, int& i1, float& v2) {
    if (v > v1) { v2 = v1; v1 = v; i1 = i; }
    else        { v2 = fmaxf(v2, v); }
}

// staging for one 32-K step of the 256x256 tile: (256 E + 256 X) rows x 32
// halves into dst (buffer = 16384 halves: E @0, X @8192). 512 threads x 4
// gld16 = 2048 x 16B. LDS dest linear per wave (base + lane*16B);
// swizzle lives in the SOURCE col: col = kts + (slot ^ P(r))*8,
// P(r) = (r ^ (r>>2)) & 3 (m-independent across the 128-row sub-blocks).
__device__ __forceinline__ void stage_step(const _Float16* __restrict__ Xh,
                                           const _Float16* __restrict__ Eh,
                                           _Float16* dst, int split, int rowBase,
                                           int S, int r0, int ldsOff, int colOff) {
    const int ntB = split * 4096 + (S >> 4) * 256;
    const int col = ((S & 15) << 5) + colOff;
    gld16(Eh + (size_t)(ntB + r0)           * DIM + col, dst + ldsOff);
    gld16(Eh + (size_t)(ntB + 128 + r0)     * DIM + col, dst + 4096 + ldsOff);
    gld16(Xh + (size_t)(rowBase + r0)       * DIM + col, dst + 8192 + ldsOff);
    gld16(Xh + (size_t)(rowBase + 128 + r0) * DIM + col, dst + 12288 + ldsOff);
}

// hi-only f16 screening pass — 8-wave 256x256 structure (measured best:
// 332 us, MfmaUtil 38.7%, no spill). Final form after exhausting the
// schedule-variant space: 5 variants all ~equal; fence-pinned pipeline
// regressed (m141); cross-barrier register prefetch is INFEASIBLE here —
// acc[4][2] = 128 AGPRs + 128 VGPRs already fills the unified 256-reg
// file (r10/r13: identical spill at any launch bound). Plateau cause:
// ~3x LDS read amplification (A frags read by 4 waves, B by 2) serialized
// against the MFMA pipe under the per-step barrier.
__launch_bounds__(512, 2)
__global__ void k_hi(const _Float16* __restrict__ Xh, const _Float16* __restrict__ Eh,
                     float* __restrict__ sV1, float* __restrict__ sV2,
                     unsigned short* __restrict__ sI1) {
    __shared__ __align__(16) _Float16 lds[4 * 16384];   // 128 KiB, 4 buffers
    __shared__ float mV[256][2], mV2[256][2];
    __shared__ int   mI[256][2];

    const int tid  = threadIdx.x;
    const int w    = tid >> 6;
    const int lane = tid & 63;
    const int wc  = w & 1;        // code half: 0 -> codes 0-127, 1 -> 128-255
    const int wrr = w >> 1;       // row quarter: rows wrr*64 .. +63
    const int c = lane & 31, h = lane >> 5;
    const int rowBase = blockIdx.x * 256;
    const int split   = blockIdx.y;

    // staging lane geometry: 4 lanes/row, 128 rows per gld16 call
    const int r0   = tid >> 2;                           // 0..127
    const int slot = tid & 3;
    const int Ps   = ((tid >> 2) ^ (tid >> 4)) & 3;      // P(r0), m-independent
    const int colOff = (slot ^ Ps) * 8;                  // pre-swizzled source col
    const int ldsOff = r0 * 32 + slot * 8;               // linear dest (lane*16B per wave)

    // read-side swizzle: slot = g ^ P(row); P(row)=Pc for all frag rows
    const int Pc = (c ^ (c >> 2)) & 3;

    float v1a = -1e30f, v2a = -1e30f, v1b = -1e30f, v2b = -1e30f;
    int i1a = 0, i1b = 0;

    // prologue: stage steps 0,1,2 (12 loads outstanding per thread)
    stage_step(Xh, Eh, &lds[0],     split, rowBase, 0, r0, ldsOff, colOff);
    stage_step(Xh, Eh, &lds[16384], split, rowBase, 1, r0, ldsOff, colOff);
    stage_step(Xh, Eh, &lds[32768], split, rowBase, 2, r0, ldsOff, colOff);

    for (int nt = 0; nt < 16; ++nt) {
        const int ntBase = split * 4096 + nt * 256;
        floatx16 acc[4][2];
        #pragma unroll
        for (int i = 0; i < 4; ++i)
            #pragma unroll
            for (int j = 0; j < 2; ++j)
                #pragma unroll
                for (int r = 0; r < 16; ++r) acc[i][j][r] = 0.f;

        #pragma unroll
        for (int k = 0; k < 16; ++k) {
            const int S = nt * 16 + k;
            // lgkm(0): step k-1's ds_reads delivered -> buffer reuse safe.
            // vmcnt(8): oldest 4 loads (= step k's tile) landed; steps
            // k+1,k+2's 8 loads stay in flight across the barrier.
            asm volatile("s_waitcnt vmcnt(8) lgkmcnt(0)" ::: "memory");
            __builtin_amdgcn_s_barrier();
            asm volatile("" ::: "memory");
            // issue stage for step S+3 (its buffer was read at step k-1)
            stage_step(Xh, Eh, &lds[((k + 3) & 3) * 16384], split, rowBase,
                       (S + 3) & 255, r0, ldsOff, colOff);
            const _Float16* B = &lds[(k & 3) * 16384];
            #pragma unroll
            for (int ks = 0; ks < 2; ++ks) {
                const int so = (((ks << 1) + h) ^ Pc) << 3;
                half8 a0 = *(const half8*)&B[(wc * 128 +  0 + c) * 32 + so];
                half8 a1 = *(const half8*)&B[(wc * 128 + 32 + c) * 32 + so];
                half8 a2 = *(const half8*)&B[(wc * 128 + 64 + c) * 32 + so];
                half8 a3 = *(const half8*)&B[(wc * 128 + 96 + c) * 32 + so];
                half8 b0 = *(const half8*)&B[8192 + (wrr * 64 +  0 + c) * 32 + so];
                half8 b1 = *(const half8*)&B[8192 + (wrr * 64 + 32 + c) * 32 + so];
                __builtin_amdgcn_s_setprio(1);
                acc[0][0] = __builtin_amdgcn_mfma_f32_32x32x16_f16(a0, b0, acc[0][0], 0, 0, 0);
                acc[1][0] = __builtin_amdgcn_mfma_f32_32x32x16_f16(a1, b0, acc[1][0], 0, 0, 0);
                acc[2][0] = __builtin_amdgcn_mfma_f32_32x32x16_f16(a2, b0, acc[2][0], 0, 0, 0);
                acc[3][0] = __builtin_amdgcn_mfma_f32_32x32x16_f16(a3, b0, acc[3][0], 0, 0, 0);
                acc[0][1] = __builtin_amdgcn_mfma_f32_32x32x16_f16(a0, b1, acc[0][1], 0, 0, 0);
                acc[1][1] = __builtin_amdgcn_mfma_f32_32x32x16_f16(a1, b1, acc[1][1], 0, 0, 0);
                acc[2][1] = __builtin_amdgcn_mfma_f32_32x32x16_f16(a2, b1, acc[2][1], 0, 0, 0);
                acc[3][1] = __builtin_amdgcn_mfma_f32_32x32x16_f16(a3, b1, acc[3][1], 0, 0, 0);
                __builtin_amdgcn_s_setprio(0);
            }
        }
        #pragma unroll
        for (int r = 0; r < 16; ++r) {
            const int codeSub = (r & 3) + ((r >> 2) << 3) + (h << 2);
            #pragma unroll
            for (int i = 0; i < 4; ++i) {
                const int code = ntBase + wc * 128 + i * 32 + codeSub;
                top2_upd(acc[i][0][r], code, v1a, i1a, v2a);
                top2_upd(acc[i][1][r], code, v1b, i1b, v2b);
            }
        }
    }

    // merge h-halves (disjoint code sets, same row)
    {
        float ov1 = __shfl_xor(v1a, 32); int oi1 = __shfl_xor(i1a, 32); float ov2 = __shfl_xor(v2a, 32);
        if (ov1 > v1a) { v2a = fmaxf(v1a, ov2); v1a = ov1; i1a = oi1; }
        else if (ov1 == v1a) { v2a = v1a; if (oi1 < i1a) i1a = oi1; }
        else { v2a = fmaxf(v2a, ov1); }
        ov1 = __shfl_xor(v1b, 32); oi1 = __shfl_xor(i1b, 32); ov2 = __shfl_xor(v2b, 32);
        if (ov1 > v1b) { v2b = fmaxf(v1b, ov2); v1b = ov1; i1b = oi1; }
        else if (ov1 == v1b) { v2b = v1b; if (oi1 < i1b) i1b = oi1; }
        else { v2b = fmaxf(v2b, ov1); }
    }
    if (h == 0) {
        const int rA = wrr * 64 + c;
        mV[rA][wc] = v1a; mV2[rA][wc] = v2a; mI[rA][wc] = i1a;
        mV[rA + 32][wc] = v1b; mV2[rA + 32][wc] = v2b; mI[rA + 32][wc] = i1b;
    }
    __syncthreads();
    if (tid < 256) {
        float v1 = mV[tid][0], v2 = mV2[tid][0]; int i1 = mI[tid][0];
        float ov1 = mV[tid][1], ov2 = mV2[tid][1]; int oi1 = mI[tid][1];
        if (ov1 > v1) { v2 = fmaxf(v1, ov2); v1 = ov1; i1 = oi1; }
        else if (ov1 == v1) { v2 = v1; if (oi1 < i1) i1 = oi1; }
        else { v2 = fmaxf(v2, ov1); }
        const int n = rowBase + tid;
        sV1[split * NROWS + n] = v1;
        sV2[split * NROWS + n] = v2;
        sI1[split * NROWS + n] = (unsigned short)i1;
    }
}

__global__ void k_top2_merge(const float* __restrict__ sV1, const float* __restrict__ sV2,
                             const unsigned short* __restrict__ sI1,
                             float* __restrict__ outIdx, int* __restrict__ list,
                             int* __restrict__ flagCnt) {
    const int n = blockIdx.x * 256 + threadIdx.x;
    float a1 = sV1[n], a2 = sV2[n]; int ai = sI1[n];
    float b1 = sV1[NROWS + n], b2 = sV2[NROWS + n]; int bi = sI1[NROWS + n];
    float best, run; int bidx;
    if (b1 > a1) { best = b1; bidx = bi; run = fmaxf(a1, b2); }
    else         { best = a1; bidx = ai; run = fmaxf(a2, b1); }
    outIdx[n] = (float)bidx;
    if (best - run < MARGIN) {
        int p = atomicAdd(flagCnt, 1);
        list[p] = n;
    }
}

__device__ __forceinline__ unsigned long long encodeKey(float v, int idx) {
    unsigned u = __float_as_uint(v);
    u = (u & 0x80000000u) ? ~u : (u | 0x80000000u);
    return ((unsigned long long)u << 32) | (unsigned)(0xFFFFFFFFu - (unsigned)idx);
}

// dual-precision rescore of flagged rows (r2-identical numerics).
__launch_bounds__(256, 2)
__global__ void k_rescore(const _Float16* __restrict__ Xh, const _Float16* __restrict__ Xl,
                          const _Float16* __restrict__ Eh, const _Float16* __restrict__ El,
                          const int* __restrict__ list, const int* __restrict__ flagCnt,
                          unsigned long long* __restrict__ rkey) {
    const int cnt = *flagCnt;
    const int t = blockIdx.x & 255;
    const int s = blockIdx.x >> 8;
    if (t * 128 >= cnt) return;

    __shared__ __align__(16) _Float16 lds[32768];  // Eh|El|Xh|Xl, 8192 halves each
    __shared__ float mV[128][2];
    __shared__ int   mI[128][2];

    const int tid  = threadIdx.x;
    const int w    = tid >> 6;
    const int lane = tid & 63;
    const int wc = w & 1, wr = w >> 1;
    const int c = lane & 31, h = lane >> 5;
    const int sr = lane >> 3;
    const int sg = (lane & 7) ^ (sr & 7);
    const int rowA = wc * 64 + c;
    const int rowB = wr * 64 + c;
    const int cx = c & 7;

    int rows_j[4];
    #pragma unroll
    for (int j = 0; j < 4; ++j) {
        const int slot = t * 128 + w * 32 + j * 8 + sr;
        rows_j[j] = (slot < cnt) ? list[slot] : 0;
    }

    float best0 = -1e30f, best1 = -1e30f;
    int bi0 = 0, bi1 = 0;
    const float SC = 1.0f / 4096.0f;

    for (int nt = 0; nt < 4; ++nt) {
        const int ntBase = s * 512 + nt * 128;

        floatx16 accH00, accH01, accH10, accH11, accC00, accC01, accC10, accC11;
        #pragma unroll
        for (int r = 0; r < 16; ++r) {
            accH00[r] = 0.f; accH01[r] = 0.f; accH10[r] = 0.f; accH11[r] = 0.f;
            accC00[r] = 0.f; accC01[r] = 0.f; accC10[r] = 0.f; accC11[r] = 0.f;
        }

        for (int chunk = 0; chunk < 8; ++chunk) {
            const int kt = chunk * 64;
            #pragma unroll
            for (int j = 0; j < 4; ++j) {
                const int rl = w * 32 + j * 8 + sr;
                const size_t gE = (size_t)(ntBase + rl) * DIM + kt + sg * 8;
                const size_t gX = (size_t)rows_j[j] * DIM + kt + sg * 8;
                _Float16* dBase = &lds[(w * 32 + j * 8) * 64];
                gld16(Eh + gE, dBase);
                gld16(El + gE, dBase + 8192);
                gld16(Xh + gX, dBase + 16384);
                gld16(Xl + gX, dBase + 24576);
            }
            __syncthreads();
            #pragma unroll
            for (int ks = 0; ks < 4; ++ks) {
                const int so = ((ks * 2 + h) ^ cx) * 8;
                const half8 ah0 = *(const half8*)&lds[rowA * 64 + so];
                const half8 ah1 = *(const half8*)&lds[(rowA + 32) * 64 + so];
                const half8 al0 = *(const half8*)&lds[8192 + rowA * 64 + so];
                const half8 al1 = *(const half8*)&lds[8192 + (rowA + 32) * 64 + so];
                const half8 bh0 = *(const half8*)&lds[16384 + rowB * 64 + so];
                const half8 bh1 = *(const half8*)&lds[16384 + (rowB + 32) * 64 + so];
                const half8 bl0 = *(const half8*)&lds[24576 + rowB * 64 + so];
                const half8 bl1 = *(const half8*)&lds[24576 + (rowB + 32) * 64 + so];

                accH00 = __builtin_amdgcn_mfma_f32_32x32x16_f16(ah0, bh0, accH00, 0, 0, 0);
                accC00 = __builtin_amdgcn_mfma_f32_32x32x16_f16(ah0, bl0, accC00, 0, 0, 0);
                accC00 = __builtin_amdgcn_mfma_f32_32x32x16_f16(al0, bh0, accC00, 0, 0, 0);

                accH01 = __builtin_amdgcn_mfma_f32_32x32x16_f16(ah0, bh1, accH01, 0, 0, 0);
                accC01 = __builtin_amdgcn_mfma_f32_32x32x16_f16(ah0, bl1, accC01, 0, 0, 0);
                accC01 = __builtin_amdgcn_mfma_f32_32x32x16_f16(al0, bh1, accC01, 0, 0, 0);

                accH10 = __builtin_amdgcn_mfma_f32_32x32x16_f16(ah1, bh0, accH10, 0, 0, 0);
                accC10 = __builtin_amdgcn_mfma_f32_32x32x16_f16(ah1, bl0, accC10, 0, 0, 0);
                accC10 = __builtin_amdgcn_mfma_f32_32x32x16_f16(al1, bh0, accC10, 0, 0, 0);

                accH11 = __builtin_amdgcn_mfma_f32_32x32x16_f16(ah1, bh1, accH11, 0, 0, 0);
                accC11 = __builtin_amdgcn_mfma_f32_32x32x16_f16(ah1, bl1, accC11, 0, 0, 0);
                accC11 = __builtin_amdgcn_mfma_f32_32x32x16_f16(al1, bh1, accC11, 0, 0, 0);
            }
            __syncthreads();
        }

        #pragma unroll
        for (int r = 0; r < 16; ++r) {
            const int codeSub = (r & 3) + ((r >> 2) << 3) + (h << 2);
            const int code0 = ntBase + wc * 64 + codeSub;
            const int code1 = code0 + 32;
            float v;
            v = fmaf(accC00[r], SC, accH00[r]);
            if (v > best0 || (v == best0 && code0 < bi0)) { best0 = v; bi0 = code0; }
            v = fmaf(accC10[r], SC, accH10[r]);
            if (v > best0 || (v == best0 && code1 < bi0)) { best0 = v; bi0 = code1; }
            v = fmaf(accC01[r], SC, accH01[r]);
            if (v > best1 || (v == best1 && code0 < bi1)) { best1 = v; bi1 = code0; }
            v = fmaf(accC11[r], SC, accH11[r]);
            if (v > best1 || (v == best1 && code1 < bi1)) { best1 = v; bi1 = code1; }
        }
    }

    {
        float ov = __shfl_xor(best0, 32); int oi = __shfl_xor(bi0, 32);
        if (ov > best0 || (ov == best0 && oi < bi0)) { best0 = ov; bi0 = oi; }
        ov = __shfl_xor(best1, 32); oi = __shfl_xor(bi1, 32);
        if (ov > best1 || (ov == best1 && oi < bi1)) { best1 = ov; bi1 = oi; }
    }
    if (h == 0) {
        mV[rowB][wc] = best0;      mI[rowB][wc] = bi0;
        mV[rowB + 32][wc] = best1; mI[rowB + 32][wc] = bi1;
    }
    __syncthreads();
    if (tid < 128) {
        const int slot = t * 128 + tid;
        if (slot < cnt) {
            float v0 = mV[tid][0]; int i0 = mI[tid][0];
            float v1 = mV[tid][1]; int i1 = mI[tid][1];
            float bv; int bidx;
            if (v1 > v0 || (v1 == v0 && i1 < i0)) { bv = v1; bidx = i1; }
            else                                  { bv = v0; bidx = i0; }
            atomicMax(&rkey[list[slot]], encodeKey(bv, bidx));
        }
    }
}

__global__ void k_rescore_merge(const unsigned long long* __restrict__ rkey,
                                const int* __restrict__ list, const int* __restrict__ flagCnt,
                                float* __restrict__ outIdx) {
    const int slot = blockIdx.x * 256 + threadIdx.x;
    if (slot < *flagCnt) {
        const int row = list[slot];
        const unsigned long long key = rkey[row];
        const int code = (int)(0xFFFFFFFFu - (unsigned)(key & 0xFFFFFFFFull));
        outIdx[row] = (float)code;
    }
}

__global__ void k_hist(const float* __restrict__ outIdx, int* __restrict__ cntI) {
    const int n = blockIdx.x * 256 + threadIdx.x;
    atomicAdd(&cntI[(int)outIdx[n]], 1);
}

// grid-strided gather + loss: 2048 blocks x 256 threads, 8 float4-groups/thread.
__global__ void k_gather_loss(const float* __restrict__ X, const _Float16* __restrict__ Eh,
                              const _Float16* __restrict__ El, const float* __restrict__ outIdx,
                              float* __restrict__ qst, float* __restrict__ lossAcc) {
    const float SC = 1.0f / 4096.0f;
    float acc = 0.f;
    #pragma unroll
    for (int it = 0; it < 8; ++it) {
        const int e = (it * 2048 + blockIdx.x) * 256 + threadIdx.x;   // float4 index
        const int row = e >> 7;                                       // 128 float4 per row
        const int col = (e & 127) * 4;
        const int k = (int)outIdx[row];
        const float4 x = ((const float4*)X)[e];
        const half4v eh = *(const half4v*)&Eh[(size_t)k * DIM + col];
        const half4v el = *(const half4v*)&El[(size_t)k * DIM + col];
        const float q0 = (float)eh.x + (float)el.x * SC;
        const float q1 = (float)eh.y + (float)el.y * SC;
        const float q2 = (float)eh.z + (float)el.z * SC;
        const float q3 = (float)eh.w + (float)el.w * SC;
        const float d0 = q0 - x.x, d1 = q1 - x.y, d2 = q2 - x.z, d3 = q3 - x.w;
        float4 o; o.x = x.x + d0; o.y = x.y + d1; o.z = x.z + d2; o.w = x.w + d3;
        ((float4*)qst)[e] = o;
        acc += d0 * d0 + d1 * d1 + d2 * d2 + d3 * d3;
    }
    const float ls = block_sum_256(acc);
    if (threadIdx.x == 0) atomicAdd(lossAcc, ls);
}

__global__ void k_cs_pre(const float* __restrict__ emacs, const int* __restrict__ cntI,
                         float* __restrict__ pre, float* __restrict__ nsum) {
    const int k = blockIdx.x * 256 + threadIdx.x;
    float p = emacs[k] * DECAYF + OMDF * (float)cntI[k];
    pre[k] = p;
    float s = block_sum_256(p);
    if (threadIdx.x == 0) atomicAdd(nsum, s);
}

__global__ void k_cs_final(const float* __restrict__ pre, const float* __restrict__ nsum,
                           float* __restrict__ outCS, float* __restrict__ csfin,
                           const float* __restrict__ lossAcc, float* __restrict__ outLoss) {
    const int k = blockIdx.x * 256 + threadIdx.x;
    float n = *nsum;
    float c = (pre[k] + EPSF) / (n + (float)KCODE * EPSF) * n;
    outCS[k] = c;
    csfin[k] = c;
    if (k == 0) *outLoss = COMMITF * (*lossAcc) / (float)(NROWS * DIM);
}

__global__ void k_scan(const int* __restrict__ cntI, int* __restrict__ offs) {
    __shared__ int ps[1024];
    const int t = threadIdx.x;
    int loc[8], pref[8], s = 0;
    #pragma unroll
    for (int j = 0; j < 8; ++j) { loc[j] = cntI[t * 8 + j]; pref[j] = s; s += loc[j]; }
    ps[t] = s;
    __syncthreads();
    for (int d = 1; d < 1024; d <<= 1) {
        int x = (t >= d) ? ps[t - d] : 0;
        __syncthreads();
        ps[t] += x;
        __syncthreads();
    }
    const int base = ps[t] - s;
    #pragma unroll
    for (int j = 0; j < 8; ++j) offs[t * 8 + j] = base + pref[j];
}

__global__ void k_bin(const float* __restrict__ outIdx, const int* __restrict__ offs,
                      int* __restrict__ cursor, int* __restrict__ perm) {
    const int n = blockIdx.x * 256 + threadIdx.x;
    const int k = (int)outIdx[n];
    const int pos = offs[k] + atomicAdd(&cursor[k], 1);
    perm[pos] = n;
}

// one block per code: dw accumulation + EMA weight + embedding, fused.
__global__ void k_dw_fused(const float* __restrict__ X, const float* __restrict__ inv_in,
                           const int* __restrict__ perm, const int* __restrict__ offs,
                           const int* __restrict__ cntI, const float* __restrict__ emaw,
                           const float* __restrict__ csfin,
                           float* __restrict__ outW, float* __restrict__ outE) {
    const int k = blockIdx.x;
    const int t = threadIdx.x;
    const int c = cntI[k];
    const int base = offs[k];
    float a0 = 0.f, a1 = 0.f;
    for (int i = 0; i < c; ++i) {
        const int row = perm[base + i];
        const float iv = inv_in[row];
        const float2 x = *(const float2*)&X[(size_t)row * DIM + t * 2];
        a0 = fmaf(x.x, iv, a0);
        a1 = fmaf(x.y, iv, a1);
    }
    const float2 w2 = *(const float2*)&emaw[(size_t)k * DIM + t * 2];
    const float w0 = w2.x * DECAYF + OMDF * a0;
    const float w1 = w2.y * DECAYF + OMDF * a1;
    float2 ow; ow.x = w0; ow.y = w1;
    *(float2*)&outW[(size_t)k * DIM + t * 2] = ow;
    const float cs = fmaxf(csfin[k], EPSF);
    float2 oe; oe.x = w0 / cs; oe.y = w1 / cs;
    *(float2*)&outE[(size_t)k * DIM + t * 2] = oe;
}

extern "C" void kernel_launch(void* const* d_in, const int* in_sizes, int n_in,
                              void* d_out, int out_size, void* d_ws, size_t ws_size,
                              hipStream_t stream) {
    const float* inputs    = (const float*)d_in[0];
    const float* embedding = (const float*)d_in[1];
    const float* emacs     = (const float*)d_in[2];
    const float* emaw      = (const float*)d_in[3];
    float* out = (float*)d_out;
    float* ws  = (float*)d_ws;

    float* inv_in  = ws;
    float* sV1     = ws + 32768;
    float* sV2     = ws + 98304;
    unsigned short* sI1 = (unsigned short*)(ws + 163840);
    int*   list    = (int*)(ws + 196608);
    int*   flagCnt = (int*)(ws + 229376);
    float* inv_emb = ws + 229440;            // overlays Xh head, dead before X norm_split
    _Float16* Xh   = (_Float16*)(ws + 229440);
    _Float16* Xl   = (_Float16*)(ws + 8618048);
    _Float16* Eh   = (_Float16*)(ws + 17006656);
    _Float16* El   = (_Float16*)(ws + 19103808);
    // overlays valid after k_top2_merge:
    unsigned long long* rkey = (unsigned long long*)(ws + 32768);
    int*   cntI    = (int*)(ws + 98304);
    int*   cursor  = (int*)(ws + 106496);
    float* lossAcc = ws + 114688;
    float* nsum    = ws + 114689;
    float* pre     = ws + 114692;
    float* csfin   = ws + 122884;
    int*   offs    = (int*)(ws + 131076);
    int*   perm    = (int*)(ws + 139268);

    float* outQst  = out;
    float* outLoss = out + 16777216;
    float* outIdx  = out + 16777217;
    float* outCS   = out + 16809985;
    float* outW    = out + 16818177;
    float* outE    = out + 21012481;

    hipMemsetAsync(flagCnt, 0, sizeof(int), stream);
    // fused norm+split: E first (its inv scratch overlays Xh head, dead after),
    // then X (clobbers that scratch; inv_in is kept for k_dw_fused).
    k_norm_split<<<KCODE / 4, 256, 0, stream>>>(embedding, inv_emb, Eh, El);
    k_norm_split<<<NROWS / 4, 256, 0, stream>>>(inputs, inv_in, Xh, Xl);
    k_hi<<<dim3(NROWS / 256, 2), 512, 0, stream>>>(Xh, Eh, sV1, sV2, sI1);
    k_top2_merge<<<NROWS / 256, 256, 0, stream>>>(sV1, sV2, sI1, outIdx, list, flagCnt);
    // zero overlays: rkey(65536) + cntI(8192) + cursor(8192) + lossAcc + nsum
    hipMemsetAsync(ws + 32768, 0, (size_t)81922 * sizeof(float), stream);
    k_rescore<<<4096, 256, 0, stream>>>(Xh, Xl, Eh, El, list, flagCnt, rkey);
    k_rescore_merge<<<NROWS / 256, 256, 0, stream>>>(rkey, list, flagCnt, outIdx);
    k_hist<<<NROWS / 256, 256, 0, stream>>>(outIdx, cntI);
    k_gather_loss<<<2048, 256, 0, stream>>>(inputs, Eh, El, outIdx, outQst, lossAcc);
    k_cs_pre<<<KCODE / 256, 256, 0, stream>>>(emacs, cntI, pre, nsum);
    k_cs_final<<<KCODE / 256, 256, 0, stream>>>(pre, nsum, outCS, csfin, lossAcc, outLoss);
    k_scan<<<1, 1024, 0, stream>>>(cntI, offs);
    k_bin<<<NROWS / 256, 256, 0, stream>>>(outIdx, offs, cursor, perm);
    k_dw_fused<<<KCODE, 256, 0, stream>>>(inputs, inv_in, perm, offs, cntI, emaw, csfin,
                                          outW, outE);
}